// Round 3
// baseline (2340.295 us; speedup 1.0000x reference)
//
#include <hip/hip_runtime.h>

// T5 encoder self-attention, fp32 baseline.
//   B=2, S=2048, D=1024, H=16, DK=64, NUM_BUCKETS=32, MAX_DISTANCE=128
// Pipeline:
//   1. bias_table_k : rel_bias[32,16] -> BT[h][delta+2047]  (16 x 4095 floats)
//   2. gemm_nt<1> x3: Q/K/V = X @ W.T scattered to [B,H,S,DK]
//   3. attn_k       : flash attention + T5 bias (online softmax), out [B,S,H*DK]
//   4. gemm_nt<0>   : out = A @ Wo.T
// Workspace: 4 x 16 MB (Q,K,V,A) + 256 KB bias table = ~64.3 MB of d_ws.

#define Bc  2
#define Sc  2048
#define Dc  1024
#define Hc  16
#define DKc 64
#define NPOS (2*Sc - 1)

// ---------------------------------------------------------------- bias table
__global__ __launch_bounds__(256) void bias_table_k(const float* __restrict__ rel_bias,
                                                    float* __restrict__ BT) {
  int idx = blockIdx.x * 256 + threadIdx.x;
  if (idx >= Hc * NPOS) return;
  int h    = idx / NPOS;
  int pos  = idx - h * NPOS;
  int delta = pos - (Sc - 1);               // k - q  (memory - context)
  int bucket = (delta > 0) ? 16 : 0;        // num_buckets//2
  int a = (delta < 0) ? -delta : delta;
  if (a < 8) {                              // max_exact = 8
    bucket += a;
  } else {
    // mirror jnp: log(a/8)/log(16)*8, fp32 ops, trunc toward zero
    float t = logf((float)a * 0.125f) / 2.772588722239781f * 8.0f;
    int rb = 8 + (int)t;
    bucket += (rb < 15) ? rb : 15;
  }
  BT[idx] = rel_bias[bucket * Hc + h];
}

// ---------------------------------------------------------------- GEMM  C = A @ W.T
// A [M,K] row-major, W [N,K] row-major (both K-contiguous -> coalesced stages).
// MODE 0: C[M,N] row-major.  MODE 1: scatter to [B,H,S,DK] (QKV layout).
template<int MODE>
__global__ __launch_bounds__(256) void gemm_nt(const float* __restrict__ A,
                                               const float* __restrict__ W,
                                               float* __restrict__ C,
                                               int M, int N, int K) {
  // k-major LDS, stride 132 floats: 16B alignment for float4 reads, +4 pad.
  __shared__ float As[16][132];
  __shared__ float Ws[16][132];
  const int t  = threadIdx.x;
  const int tx = t & 15;
  const int ty = t >> 4;
  const int row0 = blockIdx.y * 128;
  const int col0 = blockIdx.x * 128;

  float acc[8][8];
  #pragma unroll
  for (int i = 0; i < 8; i++)
    #pragma unroll
    for (int j = 0; j < 8; j++) acc[i][j] = 0.f;

  for (int k0 = 0; k0 < K; k0 += 16) {
    #pragma unroll
    for (int i = 0; i < 2; i++) {
      int f4 = i*256 + t;          // 0..511 float4s = 128 rows x 16 k
      int r  = f4 >> 2;
      int c4 = (f4 & 3) << 2;
      float4 va = *(const float4*)(A + (size_t)(row0 + r)*K + k0 + c4);
      As[c4+0][r] = va.x; As[c4+1][r] = va.y; As[c4+2][r] = va.z; As[c4+3][r] = va.w;
      float4 vw = *(const float4*)(W + (size_t)(col0 + r)*K + k0 + c4);
      Ws[c4+0][r] = vw.x; Ws[c4+1][r] = vw.y; Ws[c4+2][r] = vw.z; Ws[c4+3][r] = vw.w;
    }
    __syncthreads();
    #pragma unroll
    for (int kk = 0; kk < 16; kk++) {
      float a[8], b[8];
      *(float4*)&a[0] = *(const float4*)&As[kk][ty*8];
      *(float4*)&a[4] = *(const float4*)&As[kk][ty*8 + 4];
      *(float4*)&b[0] = *(const float4*)&Ws[kk][tx*8];
      *(float4*)&b[4] = *(const float4*)&Ws[kk][tx*8 + 4];
      #pragma unroll
      for (int i = 0; i < 8; i++)
        #pragma unroll
        for (int j = 0; j < 8; j++)
          acc[i][j] = fmaf(a[i], b[j], acc[i][j]);
    }
    __syncthreads();
  }

  #pragma unroll
  for (int i = 0; i < 8; i++) {
    int r = row0 + ty*8 + i;
    #pragma unroll
    for (int j = 0; j < 8; j += 4) {
      int c = col0 + tx*8 + j;
      float4 v = make_float4(acc[i][j], acc[i][j+1], acc[i][j+2], acc[i][j+3]);
      if (MODE == 0) {
        *(float4*)(C + (size_t)r*N + c) = v;
      } else {
        int b = r >> 11, s = r & 2047;      // m = b*S + s
        int h = c >> 6,  d = c & 63;        // n = h*DK + d (never crosses h in a 4-run)
        *(float4*)(C + ((size_t)((b*Hc + h)*Sc + s))*DKc + d) = v;
      }
    }
  }
}

// ---------------------------------------------------------------- flash attention
// Block = 256 thr = 4 waves; each wave owns 8 q rows; K-tile = 64.
// QK: lane owns k=lane, K staged transposed [d][65] (conflict-free column read),
//     q fetched via wave-uniform global addresses (scalar-cache path).
// PV: lane owns d=lane, P broadcast from per-wave LDS, V [k][64] (2-way free).
__global__ __launch_bounds__(256) void attn_k(const float* __restrict__ Q,
                                              const float* __restrict__ K,
                                              const float* __restrict__ V,
                                              const float* __restrict__ BT,
                                              float* __restrict__ O) {
  __shared__ float kT[DKc][64 + 1];
  __shared__ float Vt[64][DKc];
  __shared__ float ps[4][8][64];
  const int t    = threadIdx.x;
  const int lane = t & 63;
  const int wv   = __builtin_amdgcn_readfirstlane(t >> 6);  // wave-uniform SGPR
  const int bh   = blockIdx.x >> 6;     // 0..31  (b*16+h)
  const int qt   = blockIdx.x & 63;     // q-tile of 32
  const int h    = bh & 15;
  const int q0   = qt * 32 + wv * 8;    // this wave's first q row
  const float* Qb = Q + (size_t)bh * Sc * DKc;
  const float* Kb = K + (size_t)bh * Sc * DKc;
  const float* Vb = V + (size_t)bh * Sc * DKc;
  const float* bt = BT + h * NPOS + (Sc - 1);

  float m[8], l[8], acc[8];
  #pragma unroll
  for (int r = 0; r < 8; r++) { m[r] = -1e30f; l[r] = 0.f; acc[r] = 0.f; }

  for (int kt = 0; kt < Sc; kt += 64) {
    __syncthreads();                    // protect kT/Vt reuse across tiles
    #pragma unroll
    for (int i = 0; i < 4; i++) {
      int f4 = i*256 + t;               // 0..1023 float4s = 64 k x 16 d4
      int k  = f4 >> 4;
      int d4 = (f4 & 15) << 2;
      float4 kv = *(const float4*)(Kb + (size_t)(kt + k)*DKc + d4);
      kT[d4+0][k] = kv.x; kT[d4+1][k] = kv.y; kT[d4+2][k] = kv.z; kT[d4+3][k] = kv.w;
      *(float4*)&Vt[k][d4] = *(const float4*)(Vb + (size_t)(kt + k)*DKc + d4);
    }
    __syncthreads();

    // ---- QK^T: lane computes s[r] for k = kt+lane
    float s[8];
    #pragma unroll
    for (int r = 0; r < 8; r++) s[r] = 0.f;
    #pragma unroll
    for (int d0 = 0; d0 < DKc; d0 += 4) {
      float k0v = kT[d0+0][lane];
      float k1v = kT[d0+1][lane];
      float k2v = kT[d0+2][lane];
      float k3v = kT[d0+3][lane];
      #pragma unroll
      for (int r = 0; r < 8; r++) {
        float4 q4 = *(const float4*)(Qb + (size_t)(q0 + r)*DKc + d0); // uniform -> s_load
        s[r] = fmaf(q4.x, k0v, s[r]);
        s[r] = fmaf(q4.y, k1v, s[r]);
        s[r] = fmaf(q4.z, k2v, s[r]);
        s[r] = fmaf(q4.w, k3v, s[r]);
      }
    }

    // ---- bias + online softmax (per q row; 64-lane butterfly reduces)
    const int kabs = kt + lane;
    #pragma unroll
    for (int r = 0; r < 8; r++) {
      float sc = s[r] + bt[kabs - (q0 + r)];          // T5: no 1/sqrt(dk) scale
      float tm = sc;
      #pragma unroll
      for (int off = 32; off > 0; off >>= 1) tm = fmaxf(tm, __shfl_xor(tm, off));
      float nm = fmaxf(m[r], tm);
      float p  = __expf(sc - nm);
      float ts = p;
      #pragma unroll
      for (int off = 32; off > 0; off >>= 1) ts += __shfl_xor(ts, off);
      float cr = __expf(m[r] - nm);
      l[r]   = l[r]*cr + ts;
      m[r]   = nm;
      acc[r] *= cr;
      ps[wv][r][lane] = p;              // same-wave write->read, no barrier needed
    }

    // ---- PV: lane owns d = lane
    #pragma unroll
    for (int k0 = 0; k0 < 64; k0 += 4) {
      float v0 = Vt[k0+0][lane];
      float v1 = Vt[k0+1][lane];
      float v2 = Vt[k0+2][lane];
      float v3 = Vt[k0+3][lane];
      #pragma unroll
      for (int r = 0; r < 8; r++) {
        float4 p4 = *(const float4*)&ps[wv][r][k0];
        acc[r] = fmaf(p4.x, v0, acc[r]);
        acc[r] = fmaf(p4.y, v1, acc[r]);
        acc[r] = fmaf(p4.z, v2, acc[r]);
        acc[r] = fmaf(p4.w, v3, acc[r]);
      }
    }
  }

  // epilogue: A[b, q, h*64 + d]  (=[B,S,H*DK] row-major)
  const int b = bh >> 4;
  #pragma unroll
  for (int r = 0; r < 8; r++) {
    O[((size_t)(b*Sc + q0 + r))*Dc + h*DKc + lane] = acc[r] / l[r];
  }
}

// ---------------------------------------------------------------- launcher
extern "C" void kernel_launch(void* const* d_in, const int* in_sizes, int n_in,
                              void* d_out, int out_size, void* d_ws, size_t ws_size,
                              hipStream_t stream) {
  const float* X  = (const float*)d_in[0];   // hidden_states [2,2048,1024]
  const float* Wq = (const float*)d_in[1];
  const float* Wk = (const float*)d_in[2];
  const float* Wv = (const float*)d_in[3];
  const float* Wo = (const float*)d_in[4];
  const float* rb = (const float*)d_in[5];   // rel_bias [32,16]
  float* out = (float*)d_out;

  const size_t NQKV = (size_t)Bc * Hc * Sc * DKc;   // 4,194,304 floats
  float* ws  = (float*)d_ws;                        // needs ~64.3 MB
  float* Qw  = ws;
  float* Kw  = Qw + NQKV;
  float* Vw  = Kw + NQKV;
  float* Aw  = Vw + NQKV;
  float* BTw = Aw + NQKV;                           // 16*4095 floats

  bias_table_k<<<(Hc*NPOS + 255)/256, 256, 0, stream>>>(rb, BTw);

  dim3 g(Dc/128, (Bc*Sc)/128);                      // (8, 32) = 256 blocks
  gemm_nt<1><<<g, 256, 0, stream>>>(X,  Wq, Qw, Bc*Sc, Dc, Dc);
  gemm_nt<1><<<g, 256, 0, stream>>>(X,  Wk, Kw, Bc*Sc, Dc, Dc);
  gemm_nt<1><<<g, 256, 0, stream>>>(X,  Wv, Vw, Bc*Sc, Dc, Dc);

  attn_k<<<Bc*Hc*(Sc/32), 256, 0, stream>>>(Qw, Kw, Vw, BTw, Aw);

  gemm_nt<0><<<g, 256, 0, stream>>>(Aw, Wo, out, Bc*Sc, Dc, Dc);
}

// Round 4
// 274.402 us; speedup vs baseline: 8.5287x; 8.5287x over previous
//
#include <hip/hip_runtime.h>

// T5 encoder self-attention — fp16 MFMA everywhere, fp32 accumulate.
// B=2,S=2048,D=1024,H=16,DK=64. Pipeline:
//   bias_table -> cvt(X,Wq,Wk,Wv,Wo to fp16) -> gemm_h<1>(Q),<1>(K),<2>(V^T)
//   -> attn_m (flash, MFMA QK^T + PV, online softmax fp32) -> gemm_h<0>(out)
// ws: Xh 8MB | Wq/Wk/Wv/Wo h 2MB ea | Qh 8 | Kh 8 | VT 8 | Ah 8 | BT 0.25 = 48.3MB

#define Bc 2
#define Sc 2048
#define Dc 1024
#define Hc 16
#define DKc 64
#define NPOS (2*Sc - 1)

typedef _Float16 h8 __attribute__((ext_vector_type(8)));
typedef _Float16 h4 __attribute__((ext_vector_type(4)));
typedef float    f4 __attribute__((ext_vector_type(4)));

#define MFMA16(a,b,c) __builtin_amdgcn_mfma_f32_16x16x32_f16((a),(b),(c),0,0,0)

// async global->LDS, 16B per lane (linear LDS dest; swizzle via global source)
__device__ __forceinline__ void cp16(const void* g, void* l) {
  __builtin_amdgcn_global_load_lds((const __attribute__((address_space(1))) void*)g,
                                   (__attribute__((address_space(3))) void*)l,
                                   16, 0, 0);
}

// ---------------------------------------------------------------- bias table
__global__ __launch_bounds__(256) void bias_table_k(const float* __restrict__ rel_bias,
                                                    float* __restrict__ BT) {
  int idx = blockIdx.x * 256 + threadIdx.x;
  if (idx >= Hc * NPOS) return;
  int h    = idx / NPOS;
  int pos  = idx - h * NPOS;
  int delta = pos - (Sc - 1);               // k - q
  int bucket = (delta > 0) ? 16 : 0;
  int a = (delta < 0) ? -delta : delta;
  if (a < 8) {
    bucket += a;
  } else {
    float t = logf((float)a * 0.125f) / 2.772588722239781f * 8.0f;
    int rb = 8 + (int)t;
    bucket += (rb < 15) ? rb : 15;
  }
  BT[idx] = rel_bias[bucket * Hc + h];
}

// ---------------------------------------------------------------- fp32 -> fp16
__global__ __launch_bounds__(256) void cvt_h(const float* __restrict__ x,
                                             _Float16* __restrict__ y, int n4) {
  int i = blockIdx.x * 256 + threadIdx.x;
  if (i >= n4) return;
  float4 v = ((const float4*)x)[i];
  h4 o = {(_Float16)v.x, (_Float16)v.y, (_Float16)v.z, (_Float16)v.w};
  *(h4*)(y + (size_t)i * 4) = o;
}

// ---------------------------------------------------------------- GEMM C = A @ W^T (fp16 in, fp32 acc)
// A [M=4096][K=1024] fp16, W [N=1024][K] fp16. Tile 64(M)x128(N), BK=32.
// 256 thr = 4 waves; wave owns 64x32 cols (4 m-tiles x 2 n-tiles of 16x16).
// MODE 0: fp32 C[M][1024].  MODE 1: fp16 [B,H,S,64].  MODE 2: fp16 V^T [B,H,64,S].
template<int MODE>
__global__ __launch_bounds__(256) void gemm_h(const _Float16* __restrict__ A,
                                              const _Float16* __restrict__ W,
                                              void* __restrict__ Cp) {
  __shared__ _Float16 As[64][32];    // 4KB, 64B rows -> conflict-free b128 frags
  __shared__ _Float16 Ws[128][32];   // 8KB
  const int t  = threadIdx.x;
  const int l  = t & 63;
  const int wv = t >> 6;
  const int lr = l & 15, lg = l >> 4;
  const int bid = blockIdx.x;
  const int v = (bid & 7) * 64 + (bid >> 3);       // XCD-contiguous (512%8==0)
  const int row0 = (v >> 3) * 64;
  const int col0 = (v & 7) * 128;

  f4 acc[4][2];
  #pragma unroll
  for (int mt = 0; mt < 4; mt++)
    #pragma unroll
    for (int nt = 0; nt < 2; nt++) acc[mt][nt] = (f4){0.f, 0.f, 0.f, 0.f};

  const int srow = t >> 2;            // stage: slot g=t (+256): row=g>>2, chunk=g&3
  const int scol = (t & 3) * 8;

  for (int k0 = 0; k0 < 1024; k0 += 32) {
    __syncthreads();
    cp16(A + (size_t)(row0 + srow) * 1024 + k0 + scol, (char*)As + t * 16);
    cp16(W + (size_t)(col0 + srow) * 1024 + k0 + scol, (char*)Ws + t * 16);
    cp16(W + (size_t)(col0 + 64 + srow) * 1024 + k0 + scol, (char*)Ws + 4096 + t * 16);
    __syncthreads();                  // compiler drains vmcnt(0) before barrier

    h8 af[4], wf[2];
    #pragma unroll
    for (int mt = 0; mt < 4; mt++) af[mt] = *(const h8*)&As[mt * 16 + lr][lg * 8];
    #pragma unroll
    for (int nt = 0; nt < 2; nt++) wf[nt] = *(const h8*)&Ws[wv * 32 + nt * 16 + lr][lg * 8];
    #pragma unroll
    for (int mt = 0; mt < 4; mt++)
      #pragma unroll
      for (int nt = 0; nt < 2; nt++)
        acc[mt][nt] = MFMA16(af[mt], wf[nt], acc[mt][nt]);
  }

  #pragma unroll
  for (int mt = 0; mt < 4; mt++)
    #pragma unroll
    for (int nt = 0; nt < 2; nt++)
      #pragma unroll
      for (int j = 0; j < 4; j++) {
        int r = row0 + mt * 16 + lg * 4 + j;       // C/D: row=(l>>4)*4+j  [m89/m91]
        int c = col0 + wv * 32 + nt * 16 + lr;     //      col=l&15
        float x = acc[mt][nt][j];
        if (MODE == 0) {
          ((float*)Cp)[(size_t)r * 1024 + c] = x;
        } else {
          int b = r >> 11, s = r & 2047;
          int h = c >> 6,  d = c & 63;
          if (MODE == 1)
            ((_Float16*)Cp)[(((size_t)(b * Hc + h) * Sc + s)) * DKc + d] = (_Float16)x;
          else
            ((_Float16*)Cp)[(((size_t)(b * Hc + h) * DKc + d)) * Sc + s] = (_Float16)x;
        }
      }
}

// ---------------------------------------------------------------- flash attention (MFMA)
// 256 thr = 4 waves; wave owns 16 q-rows; KV tile 64.
// K LDS [key][64d] / V^T LDS [d][64key], both gload_lds-staged with
// source-pre-swizzle (chunk ^= row&7) so b128 frag reads are conflict-free.
// P round-trip through swizzled per-wave LDS into A-fragments.
__global__ __launch_bounds__(256) void attn_m(const _Float16* __restrict__ Q,
                                              const _Float16* __restrict__ K,
                                              const _Float16* __restrict__ VT,
                                              const float* __restrict__ BT,
                                              _Float16* __restrict__ Ah) {
  __shared__ _Float16 Ks[64][64];     // 8KB
  __shared__ _Float16 Vs[64][64];     // 8KB
  __shared__ _Float16 Pl[4][16][64];  // 8KB (2KB per wave)
  const int t  = threadIdx.x;
  const int l  = t & 63;
  const int wv = t >> 6;
  const int lr = l & 15, lg = l >> 4;
  const int v  = (blockIdx.x & 7) * 128 + (blockIdx.x >> 3);  // XCD swizzle (1024%8==0)
  const int bh = v >> 5, qt = v & 31;
  const int h = bh & 15, b = bh >> 4;
  const int q0 = qt * 64 + wv * 16;
  const _Float16* Qb = Q  + (size_t)bh * Sc * DKc;
  const _Float16* Kb = K  + (size_t)bh * Sc * DKc;
  const _Float16* Vb = VT + (size_t)bh * DKc * Sc;
  const float*    bt = BT + h * NPOS + (Sc - 1);

  // Q fragments (A-frag: row = l&15, k-run = kstep*32 + lg*8), loop-invariant
  h8 qf[2];
  qf[0] = *(const h8*)(Qb + (size_t)(q0 + lr) * 64 + lg * 8);
  qf[1] = *(const h8*)(Qb + (size_t)(q0 + lr) * 64 + 32 + lg * 8);

  f4 oacc[4];
  float m[4], lden[4];
  #pragma unroll
  for (int j = 0; j < 4; j++) { m[j] = -1e30f; lden[j] = 0.f; }
  #pragma unroll
  for (int dt = 0; dt < 4; dt++) oacc[dt] = (f4){0.f, 0.f, 0.f, 0.f};

  const int g0 = t, g1 = t + 256;                 // stage slots (linear in lane)
  const int r0 = g0 >> 3, c0 = g0 & 7;
  const int r1 = g1 >> 3, c1 = g1 & 7;

  for (int kt = 0; kt < Sc; kt += 64) {
    __syncthreads();                              // prev reads done (lgkm drained)
    cp16(Kb + (size_t)(kt + r0) * 64 + ((c0 ^ (r0 & 7)) * 8), (char*)Ks + g0 * 16);
    cp16(Kb + (size_t)(kt + r1) * 64 + ((c1 ^ (r1 & 7)) * 8), (char*)Ks + g1 * 16);
    cp16(Vb + (size_t)r0 * Sc + kt + ((c0 ^ (r0 & 7)) * 8), (char*)Vs + g0 * 16);
    cp16(Vb + (size_t)r1 * Sc + kt + ((c1 ^ (r1 & 7)) * 8), (char*)Vs + g1 * 16);
    __syncthreads();                              // vmcnt(0) drained before barrier

    // ---- QK^T: D row=q, col=key
    f4 sacc[4];
    #pragma unroll
    for (int nt = 0; nt < 4; nt++) {
      sacc[nt] = (f4){0.f, 0.f, 0.f, 0.f};
      int key = nt * 16 + lr;                     // B-frag col = l&15
      int sw = (key & 7) << 3;
      h8 kf0 = *(const h8*)&Ks[key][(lg * 8) ^ sw];
      h8 kf1 = *(const h8*)&Ks[key][(32 + lg * 8) ^ sw];
      sacc[nt] = MFMA16(qf[0], kf0, sacc[nt]);
      sacc[nt] = MFMA16(qf[1], kf1, sacc[nt]);
    }

    // ---- bias + online softmax (fp32); row = q0 + lg*4 + j, 16-lane row groups
    float sb[4][4];
    #pragma unroll
    for (int nt = 0; nt < 4; nt++)
      #pragma unroll
      for (int j = 0; j < 4; j++)
        sb[nt][j] = sacc[nt][j] + bt[kt + nt * 16 + lr - (q0 + lg * 4 + j)];

    #pragma unroll
    for (int j = 0; j < 4; j++) {
      float mx = fmaxf(fmaxf(sb[0][j], sb[1][j]), fmaxf(sb[2][j], sb[3][j]));
      #pragma unroll
      for (int off = 8; off > 0; off >>= 1) mx = fmaxf(mx, __shfl_xor(mx, off));
      float nm = fmaxf(m[j], mx);
      float cr = __expf(m[j] - nm);
      m[j] = nm;
      float ps = 0.f;
      _Float16 ph[4];
      #pragma unroll
      for (int nt = 0; nt < 4; nt++) {
        float p = __expf(sb[nt][j] - nm);
        ps += p;
        ph[nt] = (_Float16)p;
      }
      #pragma unroll
      for (int off = 8; off > 0; off >>= 1) ps += __shfl_xor(ps, off);
      lden[j] = lden[j] * cr + ps;
      #pragma unroll
      for (int dt = 0; dt < 4; dt++) oacc[dt][j] *= cr;
      int r = lg * 4 + j, swr = (r & 7) << 3;     // P: swizzled write
      #pragma unroll
      for (int nt = 0; nt < 4; nt++) Pl[wv][r][(nt * 16 + lr) ^ swr] = ph[nt];
    }

    // ---- PV: A-frag row = l&15 (same-wave LDS, in-order => no barrier)
    {
      int swp = (lr & 7) << 3;
      h8 p0 = *(const h8*)&Pl[wv][lr][(lg * 8) ^ swp];
      h8 p1 = *(const h8*)&Pl[wv][lr][(32 + lg * 8) ^ swp];
      #pragma unroll
      for (int dt = 0; dt < 4; dt++) {
        int d = dt * 16 + lr;                     // B-frag col = d
        int sw = (d & 7) << 3;
        h8 vf0 = *(const h8*)&Vs[d][(lg * 8) ^ sw];
        h8 vf1 = *(const h8*)&Vs[d][(32 + lg * 8) ^ sw];
        oacc[dt] = MFMA16(p0, vf0, oacc[dt]);
        oacc[dt] = MFMA16(p1, vf1, oacc[dt]);
      }
    }
  }

  // epilogue: Ah[b, q, h*64+d] fp16, row-major [4096][1024]
  #pragma unroll
  for (int dt = 0; dt < 4; dt++)
    #pragma unroll
    for (int j = 0; j < 4; j++) {
      int qrow = q0 + lg * 4 + j;
      Ah[(size_t)(b * Sc + qrow) * Dc + h * 64 + dt * 16 + lr] =
          (_Float16)(oacc[dt][j] / lden[j]);
    }
}

// ---------------------------------------------------------------- launcher
extern "C" void kernel_launch(void* const* d_in, const int* in_sizes, int n_in,
                              void* d_out, int out_size, void* d_ws, size_t ws_size,
                              hipStream_t stream) {
  const float* X  = (const float*)d_in[0];
  const float* Wq = (const float*)d_in[1];
  const float* Wk = (const float*)d_in[2];
  const float* Wv = (const float*)d_in[3];
  const float* Wo = (const float*)d_in[4];
  const float* rb = (const float*)d_in[5];
  float* out = (float*)d_out;

  char* ws = (char*)d_ws;
  const size_t MB = 1 << 20;
  _Float16* Xh  = (_Float16*)(ws);              // 8MB  (4M elems)
  _Float16* Wqh = (_Float16*)(ws + 8  * MB);    // 2MB
  _Float16* Wkh = (_Float16*)(ws + 10 * MB);
  _Float16* Wvh = (_Float16*)(ws + 12 * MB);
  _Float16* Woh = (_Float16*)(ws + 14 * MB);
  _Float16* Qh  = (_Float16*)(ws + 16 * MB);    // 8MB [B,H,S,64]
  _Float16* Kh  = (_Float16*)(ws + 24 * MB);    // 8MB [B,H,S,64]
  _Float16* VTh = (_Float16*)(ws + 32 * MB);    // 8MB [B,H,64,S]
  _Float16* Ahh = (_Float16*)(ws + 40 * MB);    // 8MB [4096][1024]
  float*    BTw = (float*)   (ws + 48 * MB);    // 256KB

  bias_table_k<<<(Hc * NPOS + 255) / 256, 256, 0, stream>>>(rb, BTw);

  cvt_h<<<4096, 256, 0, stream>>>(X,  Xh,  1048576);   // 4M/4
  cvt_h<<<1024, 256, 0, stream>>>(Wq, Wqh, 262144);    // 1M/4
  cvt_h<<<1024, 256, 0, stream>>>(Wk, Wkh, 262144);
  cvt_h<<<1024, 256, 0, stream>>>(Wv, Wvh, 262144);
  cvt_h<<<1024, 256, 0, stream>>>(Wo, Woh, 262144);

  gemm_h<1><<<512, 256, 0, stream>>>(Xh, Wqh, Qh);
  gemm_h<1><<<512, 256, 0, stream>>>(Xh, Wkh, Kh);
  gemm_h<2><<<512, 256, 0, stream>>>(Xh, Wvh, VTh);

  attn_m<<<1024, 256, 0, stream>>>(Qh, Kh, VTh, BTw, Ahh);

  gemm_h<0><<<512, 256, 0, stream>>>(Ahh, Woh, out);
}